// Round 1
// baseline (113.273 us; speedup 1.0000x reference)
//
#include <hip/hip_runtime.h>
#include <math.h>

#define BLOCK 256
#define BETA 0.001f

// One block per segment. Stage segment logits (<128 floats) in LDS, stride
// over pair indices, unrank k -> (i,j) of triu via triangular-number sqrt.
// l2 term is separable: sum_pairs 0.5*(pos^2+neg^2) = 0.5*(L-1)*sum(x^2).
__global__ __launch_bounds__(BLOCK) void rmloss_kernel(
    const float* __restrict__ logits,
    const int*   __restrict__ cu,
    float*       __restrict__ out,
    int n_seg, float inv_nseg)
{
    const int s = blockIdx.x;
    if (s >= n_seg) return;

    const int a = cu[s];
    const int b = cu[s + 1];
    const int L = b - a;
    const int P = (L * (L - 1)) >> 1;

    __shared__ float x[128];
    __shared__ float rs1[BLOCK / 64];
    __shared__ float rs2[BLOCK / 64];

    const int tid = threadIdx.x;

    float sq = 0.0f;
    if (tid < L) {
        float v = logits[a + tid];
        x[tid] = v;
        sq = v * v;
    }
    __syncthreads();

    // softplus(x_j - x_i) summed over this thread's pairs
    float acc = 0.0f;
    for (int k = tid; k < P; k += BLOCK) {
        int r = P - 1 - k;                       // reverse index: rows from the bottom
        int t = (int)((sqrtf(8.0f * (float)r + 1.0f) - 1.0f) * 0.5f);
        // exact fixup for float rounding (at most 1 step each way)
        while ((t + 1) * (t + 2) / 2 <= r) ++t;
        while (t * (t + 1) / 2 > r)       --t;
        const int i = L - 2 - t;
        const int j = (L - 1) - (r - (t * (t + 1)) / 2);

        const float d  = x[j] - x[i];            // neg - pos
        const float sp = fmaxf(d, 0.0f) + __logf(1.0f + __expf(-fabsf(d)));
        acc += sp;
    }

    // block reduction of (acc, sq): wave64 shuffle, then cross-wave via LDS
    float v1 = acc, v2 = sq;
    #pragma unroll
    for (int off = 32; off > 0; off >>= 1) {
        v1 += __shfl_down(v1, off, 64);
        v2 += __shfl_down(v2, off, 64);
    }
    const int lane = tid & 63;
    const int wid  = tid >> 6;
    if (lane == 0) { rs1[wid] = v1; rs2[wid] = v2; }
    __syncthreads();

    if (tid == 0) {
        float S = rs1[0] + rs1[1] + rs1[2] + rs1[3];
        float Q = rs2[0] + rs2[1] + rs2[2] + rs2[3];
        float seg = (S + 0.5f * BETA * (float)(L - 1) * Q) / (float)P;
        atomicAdd(out, seg * inv_nseg);
    }
}

extern "C" void kernel_launch(void* const* d_in, const int* in_sizes, int n_in,
                              void* d_out, int out_size, void* d_ws, size_t ws_size,
                              hipStream_t stream) {
    (void)n_in; (void)out_size; (void)d_ws; (void)ws_size;

    const float* logits = (const float*)d_in[0];
    const int*   cu     = (const int*)d_in[1];
    float*       out    = (float*)d_out;

    const int n_seg = in_sizes[1] - 1;  // cu has n_seg+1 entries

    // d_out is poisoned to 0xAA before every timed launch -> zero it.
    hipMemsetAsync(out, 0, sizeof(float), stream);

    rmloss_kernel<<<n_seg, BLOCK, 0, stream>>>(logits, cu, out, n_seg,
                                               1.0f / (float)n_seg);
}

// Round 2
// 89.922 us; speedup vs baseline: 1.2597x; 1.2597x over previous
//
#include <hip/hip_runtime.h>
#include <math.h>

#define BLOCK 256
#define BETA 0.001f

// Decomposition:
//   softplus(x_j - x_i)  (i<j)  =  0.5*h(|d|) + 0.5*(x_j - x_i)
//   where h(u) = u + 2*log(1 + exp(-u))   (symmetric in i,j)
// Sum over pairs:
//   sum_{i<j} softplus = 0.25 * sum_{i != j} h(|x_i-x_j|)   (full rectangle)
//                      + 0.5  * sum_k x_k * (2k - L + 1)    (closed form)
// l2 term is separable: sum_pairs 0.5*(pos^2+neg^2) = 0.5*(L-1)*sum(x^2).
__global__ __launch_bounds__(BLOCK) void rmloss_seg_kernel(
    const float* __restrict__ logits,
    const int*   __restrict__ cu,
    float*       __restrict__ partial)
{
    const int s = blockIdx.x;
    const int a = cu[s];
    const int L = cu[s + 1] - a;
    const int Lm1 = L - 1;
    const int R = L * Lm1;                 // ordered-rectangle size (2x pairs)

    __shared__ float x[128];
    __shared__ float r0[BLOCK / 64], r1[BLOCK / 64], r2[BLOCK / 64];

    const int tid = threadIdx.x;

    float lin = 0.0f, sq = 0.0f;
    if (tid < L) {
        float v = logits[a + tid];
        x[tid] = v;
        sq  = v * v;
        lin = v * (float)(2 * tid - Lm1);
    }
    __syncthreads();

    const float inv = 1.0f / (float)Lm1;   // block-uniform (scalar)

    float hs = 0.0f;
    for (int k = tid; k < R; k += BLOCK) {
        int i  = (int)((float)k * inv);
        int lo = i * Lm1;                  // row start; fixup at most +-1
        if (lo > k)            { --i; lo -= Lm1; }
        else if (lo + Lm1 <= k){ ++i; lo += Lm1; }
        const int jr = k - lo;
        const int j  = jr + (jr >= i);     // skip the diagonal

        const float u = fabsf(x[i] - x[j]);
        hs += u + 2.0f * __logf(1.0f + __expf(-u));
    }

    // block reduction of (hs, lin, sq)
    float v0 = hs, v1 = lin, v2 = sq;
    #pragma unroll
    for (int off = 32; off > 0; off >>= 1) {
        v0 += __shfl_down(v0, off, 64);
        v1 += __shfl_down(v1, off, 64);
        v2 += __shfl_down(v2, off, 64);
    }
    const int lane = tid & 63;
    const int wid  = tid >> 6;
    if (lane == 0) { r0[wid] = v0; r1[wid] = v1; r2[wid] = v2; }
    __syncthreads();

    if (tid == 0) {
        float HS = r0[0] + r0[1] + r0[2] + r0[3];
        float LN = r1[0] + r1[1] + r1[2] + r1[3];
        float SQ = r2[0] + r2[1] + r2[2] + r2[3];
        const float P = 0.5f * (float)R;
        partial[s] = (0.25f * HS + 0.5f * LN + 0.5f * BETA * (float)Lm1 * SQ) / P;
    }
}

__global__ __launch_bounds__(1024) void rmloss_reduce_kernel(
    const float* __restrict__ partial, float* __restrict__ out,
    int n, float inv_n)
{
    float acc = 0.0f;
    for (int k = threadIdx.x; k < n; k += 1024) acc += partial[k];
    #pragma unroll
    for (int off = 32; off > 0; off >>= 1) acc += __shfl_down(acc, off, 64);

    __shared__ float r[16];
    const int lane = threadIdx.x & 63;
    const int wid  = threadIdx.x >> 6;
    if (lane == 0) r[wid] = acc;
    __syncthreads();
    if (threadIdx.x == 0) {
        float t = 0.0f;
        #pragma unroll
        for (int w = 0; w < 16; ++w) t += r[w];
        out[0] = t * inv_n;
    }
}

extern "C" void kernel_launch(void* const* d_in, const int* in_sizes, int n_in,
                              void* d_out, int out_size, void* d_ws, size_t ws_size,
                              hipStream_t stream) {
    (void)n_in; (void)out_size; (void)ws_size;

    const float* logits = (const float*)d_in[0];
    const int*   cu     = (const int*)d_in[1];
    float*       out    = (float*)d_out;
    float*       partial = (float*)d_ws;   // n_seg floats (16 KB), rewritten fully

    const int n_seg = in_sizes[1] - 1;

    rmloss_seg_kernel<<<n_seg, BLOCK, 0, stream>>>(logits, cu, partial);
    rmloss_reduce_kernel<<<1, 1024, 0, stream>>>(partial, out, n_seg,
                                                 1.0f / (float)n_seg);
}

// Round 3
// 73.497 us; speedup vs baseline: 1.5412x; 1.2235x over previous
//
#include <hip/hip_runtime.h>
#include <math.h>

#define BETA 0.001f
#define WPB  4          // waves per block; one segment per wave

// softplus(x_j - x_i) (i<j) = 0.5*h(x_j-x_i) + 0.5*(x_j-x_i),
//   h(d) = |d| + 2*ln(1+e^{-|d|})  (symmetric, smooth: = 2 ln(2 cosh(d/2)))
// Sum over pairs:
//   sum_{i<j} softplus = 0.25*(S_full - L*h(0)) + 0.5*sum_k x_k*(2k-L+1)
//   where S_full = sum over ALL ordered (i,j) incl. diagonal, h(0)=2 ln 2.
// l2 term separable: sum_pairs 0.5*(pos^2+neg^2) = 0.5*(L-1)*sum(x^2).
//
// One wave per segment: lane t owns x[t], x[t+64] in registers; the j-loop
// reads x[j] at a wave-uniform LDS address (pure broadcast, no conflicts).
__global__ __launch_bounds__(WPB * 64) void rmloss_seg_kernel(
    const float* __restrict__ logits,
    const int*   __restrict__ cu,
    float*       __restrict__ partial,
    int n_seg)
{
    const int wave = threadIdx.x >> 6;
    const int lane = threadIdx.x & 63;
    const int s = blockIdx.x * WPB + wave;
    if (s >= n_seg) return;                    // wave-uniform

    const int a   = cu[s];
    const int L   = cu[s + 1] - a;             // 32..127
    const int Lm1 = L - 1;

    __shared__ float xs[WPB][128];
    float* __restrict__ x = xs[wave];

    const bool a_ok = lane < L;
    const bool b_ok = lane + 64 < L;
    const float va = a_ok ? logits[a + lane] : 0.0f;
    const float vb = b_ok ? logits[a + lane + 64] : 0.0f;
    x[lane]      = va;
    x[lane + 64] = vb;
    __builtin_amdgcn_wave_barrier();           // order writes before reads (free)

    const float kNL2E = -1.44269504088896340736f;  // -log2(e)
    const float kT2L2 =  1.38629436111989061883f;  //  2*ln(2)

    float acc_a = 0.0f, acc_b = 0.0f;
    if (L > 64) {
        #pragma unroll 4
        for (int j = 0; j < L; ++j) {
            const float v = x[j];
            float ua = fabsf(va - v);
            float ea = __builtin_amdgcn_exp2f(ua * kNL2E);
            acc_a += ua;
            acc_a = fmaf(kT2L2, __builtin_amdgcn_logf(1.0f + ea), acc_a);
            float ub = fabsf(vb - v);
            float eb = __builtin_amdgcn_exp2f(ub * kNL2E);
            acc_b += ub;
            acc_b = fmaf(kT2L2, __builtin_amdgcn_logf(1.0f + eb), acc_b);
        }
    } else {
        #pragma unroll 4
        for (int j = 0; j < L; ++j) {
            const float v = x[j];
            float ua = fabsf(va - v);
            float ea = __builtin_amdgcn_exp2f(ua * kNL2E);
            acc_a += ua;
            acc_a = fmaf(kT2L2, __builtin_amdgcn_logf(1.0f + ea), acc_a);
        }
    }

    const float acch = (a_ok ? acc_a : 0.0f) + (b_ok ? acc_b : 0.0f);
    const float lin  = va * (float)(2 * lane - Lm1)
                     + vb * (float)(2 * (lane + 64) - Lm1);
    const float sq   = va * va + vb * vb;

    // fused per-lane contribution, single reduction
    float f = 0.25f * acch + 0.5f * lin + (0.5f * BETA * (float)Lm1) * sq;
    #pragma unroll
    for (int off = 32; off > 0; off >>= 1)
        f += __shfl_down(f, off, 64);

    if (lane == 0) {
        const float P = 0.5f * (float)(L * Lm1);
        const float diag = 0.25f * (float)L * kT2L2;   // 0.25 * L * h(0)
        partial[s] = (f - diag) / P;
    }
}

__global__ __launch_bounds__(1024) void rmloss_reduce_kernel(
    const float* __restrict__ partial, float* __restrict__ out,
    int n, float inv_n)
{
    float acc = 0.0f;
    for (int k = threadIdx.x; k < n; k += 1024) acc += partial[k];
    #pragma unroll
    for (int off = 32; off > 0; off >>= 1) acc += __shfl_down(acc, off, 64);

    __shared__ float r[16];
    const int lane = threadIdx.x & 63;
    const int wid  = threadIdx.x >> 6;
    if (lane == 0) r[wid] = acc;
    __syncthreads();
    if (threadIdx.x == 0) {
        float t = 0.0f;
        #pragma unroll
        for (int w = 0; w < 16; ++w) t += r[w];
        out[0] = t * inv_n;
    }
}

extern "C" void kernel_launch(void* const* d_in, const int* in_sizes, int n_in,
                              void* d_out, int out_size, void* d_ws, size_t ws_size,
                              hipStream_t stream) {
    (void)n_in; (void)out_size; (void)ws_size;

    const float* logits  = (const float*)d_in[0];
    const int*   cu      = (const int*)d_in[1];
    float*       out     = (float*)d_out;
    float*       partial = (float*)d_ws;   // n_seg floats, fully rewritten

    const int n_seg  = in_sizes[1] - 1;
    const int blocks = (n_seg + WPB - 1) / WPB;

    rmloss_seg_kernel<<<blocks, WPB * 64, 0, stream>>>(logits, cu, partial, n_seg);
    rmloss_reduce_kernel<<<1, 1024, 0, stream>>>(partial, out, n_seg,
                                                 1.0f / (float)n_seg);
}

// Round 4
// 72.335 us; speedup vs baseline: 1.5659x; 1.0161x over previous
//
#include <hip/hip_runtime.h>
#include <math.h>

#define BETA 0.001f
#define WPB  4          // waves per block; one segment per wave

// softplus(x_j - x_i) (i<j) = 0.5*h(x_j-x_i) + 0.5*(x_j-x_i),
//   h(d) = |d| + 2*ln(1+e^{-|d|})
// Sum over pairs:
//   sum_{i<j} softplus = 0.25*(S_full - L*h(0)) + 0.5*sum_k x_k*(2k-L+1)
//   where S_full sums h over ALL ordered (i,j) incl. diagonal, h(0)=2 ln 2.
// l2 term separable: sum_pairs 0.5*(pos^2+neg^2) = 0.5*(L-1)*sum(x^2).
//
// Transcendental reduction: per chain accumulate
//   su = sum |d|,  p = prod (1 + e^{-|d|})   (factors in (1,2], <=127 of
//   them -> p <= 2^127 < FLT_MAX, no overflow possible)
// then  sum h = su + 2*ln2 * log2(p)  -> ONE v_log_f32 per chain total,
// one v_exp_f32 per pair (was exp+log per pair).
//
// One wave per segment: lane t owns x[t], x[t+64]; j-loop reads x[j] at a
// wave-uniform LDS address (pure broadcast, zero bank conflicts).
__global__ __launch_bounds__(WPB * 64) void rmloss_kernel(
    const float* __restrict__ logits,
    const int*   __restrict__ cu,
    float*       __restrict__ out,
    int n_seg, float inv_n)
{
    const int wave = threadIdx.x >> 6;
    const int lane = threadIdx.x & 63;
    const int s = blockIdx.x * WPB + wave;

    __shared__ float xs[WPB][128];
    __shared__ float wsum[WPB];

    const float kNL2E = -1.44269504088896340736f;  // -log2(e)
    const float kT2L2 =  1.38629436111989061883f;  //  2*ln(2)

    float segval = 0.0f;                       // lane0-of-wave contribution

    if (s < n_seg) {                           // wave-uniform guard, no return
        const int a   = cu[s];
        const int L   = cu[s + 1] - a;         // 32..127
        const int Lm1 = L - 1;

        float* __restrict__ x = xs[wave];

        const bool a_ok = lane < L;
        const bool b_ok = lane + 64 < L;
        const float va = a_ok ? logits[a + lane] : 0.0f;
        const float vb = b_ok ? logits[a + lane + 64] : 0.0f;
        x[lane]      = va;
        x[lane + 64] = vb;
        __builtin_amdgcn_wave_barrier();       // order LDS write->read (free)

        float su_a = 0.0f, p_a = 1.0f;
        float su_b = 0.0f, p_b = 1.0f;

        if (L > 64) {
            #pragma unroll 4
            for (int j = 0; j < L; ++j) {
                const float v = x[j];
                const float ua = fabsf(va - v);
                const float ea = __builtin_amdgcn_exp2f(ua * kNL2E);
                su_a += ua;
                p_a  *= 1.0f + ea;
                const float ub = fabsf(vb - v);
                const float eb = __builtin_amdgcn_exp2f(ub * kNL2E);
                su_b += ub;
                p_b  *= 1.0f + eb;
            }
        } else {
            #pragma unroll 4
            for (int j = 0; j < L; ++j) {
                const float v = x[j];
                const float ua = fabsf(va - v);
                const float ea = __builtin_amdgcn_exp2f(ua * kNL2E);
                su_a += ua;
                p_a  *= 1.0f + ea;
            }
        }

        // one log2 per chain (v_log_f32 IS log2 on gfx950)
        const float ha = su_a + kT2L2 * __builtin_amdgcn_logf(p_a);
        const float hb = su_b + kT2L2 * __builtin_amdgcn_logf(p_b);
        const float acch = (a_ok ? ha : 0.0f) + (b_ok ? hb : 0.0f);

        const float lin = va * (float)(2 * lane - Lm1)
                        + vb * (float)(2 * (lane + 64) - Lm1);
        const float sq  = va * va + vb * vb;

        float f = 0.25f * acch + 0.5f * lin + (0.5f * BETA * (float)Lm1) * sq;
        #pragma unroll
        for (int off = 32; off > 0; off >>= 1)
            f += __shfl_down(f, off, 64);

        if (lane == 0) {
            const float P    = 0.5f * (float)(L * Lm1);
            const float diag = 0.25f * (float)L * kT2L2;  // 0.25*L*h(0)
            segval = (f - diag) / P * inv_n;
        }
    }

    if (lane == 0) wsum[wave] = segval;        // out-of-range waves write 0
    __syncthreads();
    if (threadIdx.x == 0) {
        atomicAdd(out, wsum[0] + wsum[1] + wsum[2] + wsum[3]);
    }
}

extern "C" void kernel_launch(void* const* d_in, const int* in_sizes, int n_in,
                              void* d_out, int out_size, void* d_ws, size_t ws_size,
                              hipStream_t stream) {
    (void)n_in; (void)out_size; (void)d_ws; (void)ws_size;

    const float* logits = (const float*)d_in[0];
    const int*   cu     = (const int*)d_in[1];
    float*       out    = (float*)d_out;

    const int n_seg  = in_sizes[1] - 1;
    const int blocks = (n_seg + WPB - 1) / WPB;

    hipMemsetAsync(out, 0, sizeof(float), stream);   // d_out re-poisoned 0xAA
    rmloss_kernel<<<blocks, WPB * 64, 0, stream>>>(logits, cu, out, n_seg,
                                                   1.0f / (float)n_seg);
}